// Round 14
// baseline (2398.731 us; speedup 1.0000x reference)
//
#include <hip/hip_runtime.h>

#define N_NODES 500000
#define NGRAPH  64
#define FDIM    16
typedef unsigned int u32;

// ---------- per-node projections: a = x.w_neigh0, s = x.w_self0 ----------
__global__ __launch_bounds__(256) void proj_kernel(const float* __restrict__ x,
                                                   const float* __restrict__ wn,
                                                   const float* __restrict__ wsf,
                                                   float* __restrict__ a,
                                                   float* __restrict__ s) {
    int i = blockIdx.x * blockDim.x + threadIdx.x;
    if (i >= N_NODES) return;
    const float4* xr = (const float4*)(x + (size_t)i * FDIM);
    float4 v0 = xr[0], v1 = xr[1], v2 = xr[2], v3 = xr[3];
    const float4* n4 = (const float4*)wn;
    const float4* s4 = (const float4*)wsf;
    float4 n0 = n4[0], n1 = n4[1], n2 = n4[2], n3 = n4[3];
    float4 w0 = s4[0], w1 = s4[1], w2 = s4[2], w3 = s4[3];
    float an = v0.x*n0.x + v0.y*n0.y + v0.z*n0.z + v0.w*n0.w
             + v1.x*n1.x + v1.y*n1.y + v1.z*n1.z + v1.w*n1.w
             + v2.x*n2.x + v2.y*n2.y + v2.z*n2.z + v2.w*n2.w
             + v3.x*n3.x + v3.y*n3.y + v3.z*n3.z + v3.w*n3.w;
    float as = v0.x*w0.x + v0.y*w0.y + v0.z*w0.z + v0.w*w0.w
             + v1.x*w1.x + v1.y*w1.y + v1.z*w1.z + v1.w*w1.w
             + v2.x*w2.x + v2.y*w2.y + v2.z*w2.z + v2.w*w2.w
             + v3.x*w3.x + v3.y*w3.y + v3.z*w3.z + v3.w*w3.w;
    a[i] = an;
    s[i] = as;
}

// ---------- edge pass: native global f32 atomics (global_atomic_add_f32) ----------
__global__ __launch_bounds__(256) void edge_native(const int* __restrict__ src,
                                                   const int* __restrict__ dst,
                                                   const float* __restrict__ ew,
                                                   const float* __restrict__ h,
                                                   float* __restrict__ agg, int E) {
    int nq = E >> 2;
    int stride = gridDim.x * blockDim.x;
    const int4*   s4 = (const int4*)src;
    const int4*   d4 = (const int4*)dst;
    const float4* w4 = (const float4*)ew;
    for (int i = blockIdx.x * blockDim.x + threadIdx.x; i < nq; i += stride) {
        int4   ss = s4[i];
        int4   dd = d4[i];
        float4 ww = w4[i];
        float g0 = h[ss.x];
        float g1 = h[ss.y];
        float g2 = h[ss.z];
        float g3 = h[ss.w];
        unsafeAtomicAdd(&agg[dd.x], g0 * ww.x);
        unsafeAtomicAdd(&agg[dd.y], g1 * ww.y);
        unsafeAtomicAdd(&agg[dd.z], g2 * ww.z);
        unsafeAtomicAdd(&agg[dd.w], g3 * ww.w);
    }
    int t0 = nq << 2;
    for (int i = t0 + blockIdx.x * blockDim.x + threadIdx.x; i < E; i += stride)
        unsafeAtomicAdd(&agg[dst[i]], h[src[i]] * ew[i]);
}

// ---------- node update: h = relu(agg*scale + b + self*wself), optional fused graph sum ----------
template<bool LAST>
__global__ __launch_bounds__(256) void node_update(const float* __restrict__ agg,
                                                   const float* __restrict__ selfv,
                                                   const float* __restrict__ wnp,  // scalar or nullptr (=1)
                                                   const float* __restrict__ bp,   // scalar bias
                                                   const float* __restrict__ wsp,  // scalar or nullptr (=1)
                                                   float* __restrict__ hout,
                                                   const int* __restrict__ gid,
                                                   float* __restrict__ hg) {
    int n = blockIdx.x * blockDim.x + threadIdx.x;
    if (n >= N_NODES) return;
    float scale = wnp ? wnp[0] : 1.0f;
    float wself = wsp ? wsp[0] : 1.0f;
    float v = fmaxf(agg[n] * scale + bp[0] + selfv[n] * wself, 0.0f);
    hout[n] = v;
    if (LAST) {
        int g = gid[n];
        unsigned long long act = __ballot(1);
        int g0 = __shfl(g, 0);
        if (act == ~0ull && __all(g == g0)) {
            float t = v;
#pragma unroll
            for (int o = 32; o > 0; o >>= 1) t += __shfl_down(t, o);
            if ((threadIdx.x & 63) == 0) unsafeAtomicAdd(&hg[g0], t);
        } else {
            unsafeAtomicAdd(&hg[g], v);
        }
    }
}

// ---------- head MLP + log_softmax ----------
__global__ void head_kernel(const float* __restrict__ hg,
                            const float* __restrict__ fc1w, const float* __restrict__ fc1b,
                            const float* __restrict__ outw, const float* __restrict__ outb,
                            float* __restrict__ out) {
    int g = threadIdx.x;
    if (g >= NGRAPH) return;
    float v = hg[g];
    float t[8];
#pragma unroll
    for (int j = 0; j < 8; ++j) {
        float z = (v * fc1w[j] + fc1b[j]) * 1000.0f;
        t[j] = 1.0f / (1.0f + expf(-z));
    }
    float o[4];
#pragma unroll
    for (int k = 0; k < 4; ++k) {
        float acc2 = outb[k];
#pragma unroll
        for (int j = 0; j < 8; ++j) acc2 += t[j] * outw[k * 8 + j];
        o[k] = fmaxf(acc2, 0.0f);
    }
    float m = fmaxf(fmaxf(o[0], o[1]), fmaxf(o[2], o[3]));
    float se = 0.0f;
#pragma unroll
    for (int k = 0; k < 4; ++k) se += expf(o[k] - m);
    float lse = m + logf(se);
#pragma unroll
    for (int k = 0; k < 4; ++k) out[g * 4 + k] = o[k] - lse;
}

extern "C" void kernel_launch(void* const* d_in, const int* in_sizes, int n_in,
                              void* d_out, int out_size, void* d_ws, size_t ws_size,
                              hipStream_t stream) {
    const float* x    = (const float*)d_in[0];
    const int*   src  = (const int*)  d_in[1];
    const int*   dst  = (const int*)  d_in[2];
    const int*   gid  = (const int*)  d_in[3];
    const float* ew   = (const float*)d_in[4];
    const float* wn0  = (const float*)d_in[6];
    const float* b0   = (const float*)d_in[7];
    const float* ws0  = (const float*)d_in[8];
    const float* wn1  = (const float*)d_in[9];
    const float* b1   = (const float*)d_in[10];
    const float* ws1  = (const float*)d_in[11];
    const float* wn2  = (const float*)d_in[12];
    const float* b2   = (const float*)d_in[13];
    const float* ws2  = (const float*)d_in[14];
    const float* fc1w = (const float*)d_in[15];
    const float* fc1b = (const float*)d_in[16];
    const float* outw = (const float*)d_in[17];
    const float* outb = (const float*)d_in[18];
    int E = in_sizes[1];

    const int BLK = 256;
    int nodeGrid = (N_NODES + BLK - 1) / BLK;
    int edgeGrid = 4096;

    // workspace: agg, a, s, hg  (~6 MB)
    char* ws = (char*)d_ws;
    size_t off = 0;
    float* agg = (float*)(ws + off); off += (size_t)N_NODES * 4;
    float* a   = (float*)(ws + off); off += (size_t)N_NODES * 4;
    float* s   = (float*)(ws + off); off += (size_t)N_NODES * 4;
    float* hg  = (float*)(ws + off); off += 256;

    // projections: a = x.wn0, s = x.ws0
    proj_kernel<<<nodeGrid, BLK, 0, stream>>>(x, wn0, ws0, a, s);
    (void)hipMemsetAsync(hg, 0, NGRAPH * sizeof(float), stream);

    // layer 0: agg = segsum(a[src]*ew); s = relu(agg + b0 + s)
    (void)hipMemsetAsync(agg, 0, (size_t)N_NODES * sizeof(float), stream);
    edge_native<<<edgeGrid, BLK, 0, stream>>>(src, dst, ew, a, agg, E);
    node_update<false><<<nodeGrid, BLK, 0, stream>>>(agg, s, nullptr, b0, nullptr, s, gid, hg);

    // layer 1: agg = segsum(s[src]*ew); s = relu(agg*wn1 + b1 + s*ws1)
    (void)hipMemsetAsync(agg, 0, (size_t)N_NODES * sizeof(float), stream);
    edge_native<<<edgeGrid, BLK, 0, stream>>>(src, dst, ew, s, agg, E);
    node_update<false><<<nodeGrid, BLK, 0, stream>>>(agg, s, wn1, b1, ws1, s, gid, hg);

    // layer 2 (+ fused per-graph sum)
    (void)hipMemsetAsync(agg, 0, (size_t)N_NODES * sizeof(float), stream);
    edge_native<<<edgeGrid, BLK, 0, stream>>>(src, dst, ew, s, agg, E);
    node_update<true><<<nodeGrid, BLK, 0, stream>>>(agg, s, wn2, b2, ws2, s, gid, hg);

    // head
    head_kernel<<<1, 64, 0, stream>>>(hg, fc1w, fc1b, outw, outb, (float*)d_out);
}

// Round 15
// 464.051 us; speedup vs baseline: 5.1691x; 5.1691x over previous
//
#include <hip/hip_runtime.h>

#define N_NODES 500000
#define NGRAPH  64
#define FDIM    16
#define NB1     62                 // dst bins
#define NPB1    8192               // nodes per bin
#define SH1     13
#define SLC     8                  // slices per bin in bin_pass
#define NBLK    1024               // binning blocks
#define CH      4096               // staged-scatter chunk (edges)
typedef unsigned int u32;
typedef unsigned long long u64;

// ---------- fused: hist (blocks 0..NBLK-1, lane-spread 8-way sub-hist) + projections ----------
__global__ __launch_bounds__(1024) void proj_hist(const int* __restrict__ dst, int E, int chunk,
                                                  u32* __restrict__ blockHist,
                                                  const float* __restrict__ x,
                                                  const float* __restrict__ wn,
                                                  const float* __restrict__ wsf,
                                                  float* __restrict__ a,
                                                  float* __restrict__ s) {
    __shared__ u32 cnt[8][64];
    if (blockIdx.x < NBLK) {
        int tid = threadIdx.x;
        for (int t = tid; t < 8 * 64; t += 1024) ((u32*)cnt)[t] = 0;
        __syncthreads();
        int rep = tid & 7;                       // lane-spread: within-wave collisions /8
        int b = blockIdx.x;
        int lo = b * chunk, hi = min(lo + chunk, E);
        int m = (hi - lo) & ~3;
        for (int i = lo + tid * 4; i < lo + m; i += 4096) {
            int4 d = *(const int4*)(dst + i);
            atomicAdd(&cnt[rep][((u32)d.x) >> SH1], 1u);
            atomicAdd(&cnt[rep][((u32)d.y) >> SH1], 1u);
            atomicAdd(&cnt[rep][((u32)d.z) >> SH1], 1u);
            atomicAdd(&cnt[rep][((u32)d.w) >> SH1], 1u);
        }
        for (int i = lo + m + tid; i < hi; i += 1024)
            atomicAdd(&cnt[rep][((u32)dst[i]) >> SH1], 1u);
        __syncthreads();
        if (tid < NB1) {
            u32 tot = 0;
#pragma unroll
            for (int r = 0; r < 8; ++r) tot += cnt[r][tid];
            blockHist[(size_t)b * NB1 + tid] = tot;
        }
    } else {
        int i = (blockIdx.x - NBLK) * 1024 + threadIdx.x;
        if (i >= N_NODES) return;
        const float4* xr = (const float4*)(x + (size_t)i * FDIM);
        float4 v0 = xr[0], v1 = xr[1], v2 = xr[2], v3 = xr[3];
        const float4* n4 = (const float4*)wn;
        const float4* s4 = (const float4*)wsf;
        float4 n0 = n4[0], n1 = n4[1], n2 = n4[2], n3 = n4[3];
        float4 w0 = s4[0], w1 = s4[1], w2 = s4[2], w3 = s4[3];
        float an = v0.x*n0.x + v0.y*n0.y + v0.z*n0.z + v0.w*n0.w
                 + v1.x*n1.x + v1.y*n1.y + v1.z*n1.z + v1.w*n1.w
                 + v2.x*n2.x + v2.y*n2.y + v2.z*n2.z + v2.w*n2.w
                 + v3.x*n3.x + v3.y*n3.y + v3.z*n3.z + v3.w*n3.w;
        float as = v0.x*w0.x + v0.y*w0.y + v0.z*w0.z + v0.w*w0.w
                 + v1.x*w1.x + v1.y*w1.y + v1.z*w1.z + v1.w*w1.w
                 + v2.x*w2.x + v2.y*w2.y + v2.z*w2.z + v2.w*w2.w
                 + v3.x*w3.x + v3.y*w3.y + v3.z*w3.z + v3.w*w3.w;
        a[i] = an;
        s[i] = as;
    }
}

// ---------- per-bin exclusive scan over NBLK blocks ----------
__global__ __launch_bounds__(NBLK) void scan1_kernel(u32* __restrict__ blockHist,
                                                     u32* __restrict__ binTotal) {
    int j = blockIdx.x;
    __shared__ u32 lsum[NBLK];
    int t = threadIdx.x;
    u32 v = blockHist[(size_t)t * NB1 + j];
    lsum[t] = v;
    __syncthreads();
    u32 x = v;
    for (int off = 1; off < NBLK; off <<= 1) {
        u32 y = (t >= off) ? lsum[t - off] : 0u;
        __syncthreads();
        x += y; lsum[t] = x;
        __syncthreads();
    }
    if (t == NBLK - 1) binTotal[j] = x;
    blockHist[(size_t)t * NB1 + j] = x - v;
}

// ---------- exclusive scan over bin totals ----------
__global__ void scan2_kernel(const u32* __restrict__ binTotal, u32* __restrict__ binStart) {
    __shared__ u32 sh[64];
    int t = threadIdx.x;
    u32 v = (t < NB1) ? binTotal[t] : 0u;
    sh[t] = v;
    __syncthreads();
    for (int d = 1; d < 64; d <<= 1) {
        u32 y = (t >= d) ? sh[t - d] : 0u;
        __syncthreads();
        sh[t] += y;
        __syncthreads();
    }
    if (t < NB1) binStart[t] = sh[t] - v;
    if (t == 63) binStart[NB1] = sh[63];
}

// ---------- LDS-staged scatter (CH=4096, r8-proven shape) ----------
__global__ __launch_bounds__(512) void scatter_staged(const int* __restrict__ src,
                                                      const int* __restrict__ dst,
                                                      const float* __restrict__ ew,
                                                      int E, int chunk,
                                                      const u32* __restrict__ blockHist,
                                                      const u32* __restrict__ binStart,
                                                      u64* __restrict__ binned) {
    __shared__ u32 cursor[64];
    __shared__ u32 cnt[64];
    __shared__ u32 off[64];
    __shared__ u64 stage[CH];
    __shared__ unsigned char binOf[CH];
    int b = blockIdx.x, tid = threadIdx.x;
    if (tid < NB1) cursor[tid] = binStart[tid] + blockHist[(size_t)b * NB1 + tid];
    int lo = b * chunk, hiB = min(lo + chunk, E);
    for (int base = lo; base < hiB; base += CH) {
        int n = min(CH, hiB - base);
        if (tid < 64) cnt[tid] = 0;
        __syncthreads();
        u32 rec[8]; float wv[8]; u32 bi[8], rk[8];
#pragma unroll
        for (int k = 0; k < 8; ++k) {
            int idx = base + k * 512 + tid;
            bi[k] = 0xFFFFFFFFu;
            if (idx < base + n) {
                u32 d  = (u32)dst[idx];
                bi[k]  = d >> SH1;
                rec[k] = ((u32)src[idx]) | ((d & (NPB1 - 1)) << 19);
                wv[k]  = ew[idx];
                rk[k]  = atomicAdd(&cnt[bi[k]], 1u);
            }
        }
        __syncthreads();
        if (tid < 64) off[tid] = cnt[tid];
        __syncthreads();
        for (int d2 = 1; d2 < 64; d2 <<= 1) {
            u32 y = 0;
            if (tid < 64 && tid >= d2) y = off[tid - d2];
            __syncthreads();
            if (tid < 64) off[tid] += y;
            __syncthreads();
        }
        if (tid < 64) off[tid] -= cnt[tid];
        __syncthreads();
#pragma unroll
        for (int k = 0; k < 8; ++k) {
            if (bi[k] != 0xFFFFFFFFu) {
                u32 p = off[bi[k]] + rk[k];
                stage[p] = (u64)rec[k] | ((u64)__float_as_uint(wv[k]) << 32);
                binOf[p] = (unsigned char)bi[k];
            }
        }
        __syncthreads();
        for (int p = tid; p < n; p += 512) {
            u32 jj = binOf[p];
            binned[cursor[jj] + ((u32)p - off[jj])] = stage[p];
        }
        __syncthreads();
        if (tid < NB1) cursor[tid] += cnt[tid];
        __syncthreads();
    }
}

// ---------- per-layer: gather + LDS-atomic accumulate ----------
__global__ __launch_bounds__(512) void bin_pass(const u64* __restrict__ binned,
                                                const u32* __restrict__ binStart,
                                                const float* __restrict__ hsrc,
                                                float* __restrict__ partials) {
    __shared__ float acc[NPB1];        // 32 KB
    int j = blockIdx.x / SLC, sl = blockIdx.x % SLC;
    for (int t = threadIdx.x; t < NPB1; t += 512) acc[t] = 0.0f;
    __syncthreads();
    u32 blo = binStart[j], bhi = binStart[j + 1];
    u32 cj = bhi - blo;
    u32 per = (cj + SLC - 1) / SLC;
    u32 lo = blo + sl * per;
    u32 hi = min(lo + per, bhi);
    u32 i = lo + threadIdx.x;
    for (; i + 7u * 512u < hi; i += 8u * 512u) {
        u64 e[8];
#pragma unroll
        for (int k = 0; k < 8; ++k) e[k] = __builtin_nontemporal_load(&binned[i + (u32)k * 512u]);
        float g[8];
#pragma unroll
        for (int k = 0; k < 8; ++k) g[k] = hsrc[((u32)e[k]) & 0x7FFFFu];
#pragma unroll
        for (int k = 0; k < 8; ++k)
            unsafeAtomicAdd(&acc[((u32)e[k]) >> 19], g[k] * __uint_as_float((u32)(e[k] >> 32)));
    }
    for (; i < hi; i += 512) {
        u64 e = __builtin_nontemporal_load(&binned[i]);
        unsafeAtomicAdd(&acc[((u32)e) >> 19],
                        hsrc[((u32)e) & 0x7FFFFu] * __uint_as_float((u32)(e >> 32)));
    }
    __syncthreads();
    float* p = partials + ((size_t)j * SLC + sl) * NPB1;
    for (int t = threadIdx.x; t < NPB1; t += 512)
        __builtin_nontemporal_store(acc[t], &p[t]);
}

// ---------- merge slices + bias + self-loop + relu (ping-pong out, fused graph sum) ----------
template<bool LAST>
__global__ __launch_bounds__(256) void merge_update(const float* __restrict__ partials,
                                                    const float* __restrict__ selfv,
                                                    const float* __restrict__ wnp,
                                                    const float* __restrict__ bp,
                                                    const float* __restrict__ wsp,
                                                    float* __restrict__ hout,
                                                    const int* __restrict__ gid,
                                                    float* __restrict__ hg) {
    int n = blockIdx.x * blockDim.x + threadIdx.x;
    if (n >= N_NODES) return;
    int j = n >> SH1;
    int l = n & (NPB1 - 1);
    const float* p = partials + ((size_t)j * SLC) * NPB1 + l;
    float sum = 0.0f;
#pragma unroll
    for (int k = 0; k < SLC; ++k) sum += __builtin_nontemporal_load(&p[k * NPB1]);
    float scale = wnp ? wnp[0] : 1.0f;
    float wself = wsp ? wsp[0] : 1.0f;
    float v = fmaxf(sum * scale + bp[0] + selfv[n] * wself, 0.0f);
    hout[n] = v;
    if (LAST) {
        int g = gid[n];
        unsigned long long act = __ballot(1);
        int g0 = __shfl(g, 0);
        if (act == ~0ull && __all(g == g0)) {
            float t = v;
#pragma unroll
            for (int o = 32; o > 0; o >>= 1) t += __shfl_down(t, o);
            if ((threadIdx.x & 63) == 0) unsafeAtomicAdd(&hg[g0], t);
        } else {
            unsafeAtomicAdd(&hg[g], v);
        }
    }
}

// ---------- fallback (global atomics) ----------
__global__ void edge_pass(const int* __restrict__ src, const int* __restrict__ dst,
                          const float* __restrict__ ew, const float* __restrict__ h,
                          float* __restrict__ agg, const float* __restrict__ wnp, int E) {
    float scale = wnp ? wnp[0] : 1.0f;
    int stride = gridDim.x * blockDim.x;
    for (int i = blockIdx.x * blockDim.x + threadIdx.x; i < E; i += stride)
        unsafeAtomicAdd(&agg[dst[i]], h[src[i]] * ew[i] * scale);
}
__global__ void node_update(const float* __restrict__ agg, const float* __restrict__ selfv,
                            const float* __restrict__ bp, const float* __restrict__ wsp,
                            float* __restrict__ hout) {
    int i = blockIdx.x * blockDim.x + threadIdx.x;
    if (i >= N_NODES) return;
    float wsc = wsp ? wsp[0] : 1.0f;
    hout[i] = fmaxf(agg[i] + bp[0] + selfv[i] * wsc, 0.0f);
}
__global__ void proj_kernel(const float* __restrict__ x, const float* __restrict__ wn,
                            const float* __restrict__ wsf, float* __restrict__ a,
                            float* __restrict__ s) {
    int i = blockIdx.x * blockDim.x + threadIdx.x;
    if (i >= N_NODES) return;
    float an = 0.f, as = 0.f;
    for (int k = 0; k < FDIM; ++k) {
        float v = x[(size_t)i * FDIM + k];
        an += v * wn[k]; as += v * wsf[k];
    }
    a[i] = an; s[i] = as;
}
__global__ __launch_bounds__(256) void graph_sum(const float* __restrict__ h,
                                                 const int* __restrict__ gid,
                                                 float* __restrict__ hg) {
    __shared__ float loc[NGRAPH];
    int t = threadIdx.x;
    if (t < NGRAPH) loc[t] = 0.0f;
    __syncthreads();
    int nq = N_NODES / 4;
    int stride = gridDim.x * blockDim.x;
    for (int q = blockIdx.x * blockDim.x + t; q < nq; q += stride) {
        int4   g4 = *(const int4*)(gid + 4 * q);
        float4 h4 = *(const float4*)(h + 4 * q);
        int g0 = __shfl(g4.x, 0);
        bool uni = (g4.x == g0) & (g4.w == g0);
        if (__all(uni)) {
            float v = h4.x + h4.y + h4.z + h4.w;
#pragma unroll
            for (int o = 32; o > 0; o >>= 1) v += __shfl_down(v, o);
            if ((t & 63) == 0) unsafeAtomicAdd(&loc[g0], v);
        } else {
            unsafeAtomicAdd(&loc[g4.x], h4.x);
            unsafeAtomicAdd(&loc[g4.y], h4.y);
            unsafeAtomicAdd(&loc[g4.z], h4.z);
            unsafeAtomicAdd(&loc[g4.w], h4.w);
        }
    }
    __syncthreads();
    if (t < NGRAPH) unsafeAtomicAdd(&hg[t], loc[t]);
}

// ---------- head MLP + log_softmax ----------
__global__ void head_kernel(const float* __restrict__ hg,
                            const float* __restrict__ fc1w, const float* __restrict__ fc1b,
                            const float* __restrict__ outw, const float* __restrict__ outb,
                            float* __restrict__ out) {
    int g = threadIdx.x;
    if (g >= NGRAPH) return;
    float v = hg[g];
    float t[8];
#pragma unroll
    for (int j = 0; j < 8; ++j) {
        float z = (v * fc1w[j] + fc1b[j]) * 1000.0f;
        t[j] = 1.0f / (1.0f + expf(-z));
    }
    float o[4];
#pragma unroll
    for (int k = 0; k < 4; ++k) {
        float acc2 = outb[k];
#pragma unroll
        for (int j = 0; j < 8; ++j) acc2 += t[j] * outw[k * 8 + j];
        o[k] = fmaxf(acc2, 0.0f);
    }
    float m = fmaxf(fmaxf(o[0], o[1]), fmaxf(o[2], o[3]));
    float se = 0.0f;
#pragma unroll
    for (int k = 0; k < 4; ++k) se += expf(o[k] - m);
    float lse = m + logf(se);
#pragma unroll
    for (int k = 0; k < 4; ++k) out[g * 4 + k] = o[k] - lse;
}

extern "C" void kernel_launch(void* const* d_in, const int* in_sizes, int n_in,
                              void* d_out, int out_size, void* d_ws, size_t ws_size,
                              hipStream_t stream) {
    const float* x    = (const float*)d_in[0];
    const int*   src  = (const int*)  d_in[1];
    const int*   dst  = (const int*)  d_in[2];
    const int*   gid  = (const int*)  d_in[3];
    const float* ew   = (const float*)d_in[4];
    const float* wn0  = (const float*)d_in[6];
    const float* b0   = (const float*)d_in[7];
    const float* ws0  = (const float*)d_in[8];
    const float* wn1  = (const float*)d_in[9];
    const float* b1   = (const float*)d_in[10];
    const float* ws1  = (const float*)d_in[11];
    const float* wn2  = (const float*)d_in[12];
    const float* b2   = (const float*)d_in[13];
    const float* ws2  = (const float*)d_in[14];
    const float* fc1w = (const float*)d_in[15];
    const float* fc1b = (const float*)d_in[16];
    const float* outw = (const float*)d_in[17];
    const float* outb = (const float*)d_in[18];
    int E = in_sizes[1];

    const int BLK = 256;
    int nodeGrid = (N_NODES + BLK - 1) / BLK;
    char* ws = (char*)d_ws;

    size_t off = 0;
    u64* binned     = (u64*)(ws + off); off += (size_t)E * 8;
    u32* blockHist  = (u32*)(ws + off); off += (size_t)NBLK * NB1 * 4;
    u32* binStart   = (u32*)(ws + off); off += (NB1 + 2) * 4;
    off = (off + 63) & ~(size_t)63;
    u32* binTotal   = (u32*)(ws + off); off += (NB1 + 2) * 4;
    off = (off + 63) & ~(size_t)63;
    float* partials = (float*)(ws + off); off += (size_t)NB1 * SLC * NPB1 * 4;
    float* a  = (float*)(ws + off); off += (size_t)N_NODES * 4;
    float* s  = (float*)(ws + off); off += (size_t)N_NODES * 4;
    float* h0 = (float*)(ws + off); off += (size_t)N_NODES * 4;
    float* h1 = (float*)(ws + off); off += (size_t)N_NODES * 4;
    float* hg = (float*)(ws + off); off += 256;
    size_t need = off;

    if (ws_size >= need) {
        int chunk = (((E + NBLK - 1) / NBLK) + 3) & ~3;
        int projBlocks = (N_NODES + 1023) / 1024;

        proj_hist<<<NBLK + projBlocks, 1024, 0, stream>>>(dst, E, chunk, blockHist,
                                                          x, wn0, ws0, a, s);
        scan1_kernel<<<NB1, NBLK, 0, stream>>>(blockHist, binTotal);
        scan2_kernel<<<1, 64, 0, stream>>>(binTotal, binStart);
        scatter_staged<<<NBLK, 512, 0, stream>>>(src, dst, ew, E, chunk, blockHist,
                                                 binStart, binned);
        (void)hipMemsetAsync(hg, 0, NGRAPH * sizeof(float), stream);

        // layer 0: neigh from a, self from s -> h0
        bin_pass<<<NB1 * SLC, 512, 0, stream>>>(binned, binStart, a, partials);
        merge_update<false><<<nodeGrid, BLK, 0, stream>>>(partials, s, nullptr, b0, nullptr,
                                                          h0, gid, hg);
        // layer 1: h0 -> h1
        bin_pass<<<NB1 * SLC, 512, 0, stream>>>(binned, binStart, h0, partials);
        merge_update<false><<<nodeGrid, BLK, 0, stream>>>(partials, h0, wn1, b1, ws1,
                                                          h1, gid, hg);
        // layer 2: h1 -> h0 (+ fused graph sum)
        bin_pass<<<NB1 * SLC, 512, 0, stream>>>(binned, binStart, h1, partials);
        merge_update<true><<<nodeGrid, BLK, 0, stream>>>(partials, h1, wn2, b2, ws2,
                                                         h0, gid, hg);

        head_kernel<<<1, 64, 0, stream>>>(hg, fc1w, fc1b, outw, outb, (float*)d_out);
    } else {
        // fallback: global-atomic path
        float* wsb  = (float*)d_ws;
        float* fa   = wsb;
        float* fs   = wsb + 1 * (size_t)N_NODES;
        float* fagg = wsb + 2 * (size_t)N_NODES;
        float* fh   = wsb + 3 * (size_t)N_NODES;
        float* fhg  = wsb + 4 * (size_t)N_NODES;

        proj_kernel<<<nodeGrid, BLK, 0, stream>>>(x, wn0, ws0, fa, fs);

        (void)hipMemsetAsync(fagg, 0, (size_t)N_NODES * sizeof(float), stream);
        edge_pass<<<4096, BLK, 0, stream>>>(src, dst, ew, fa, fagg, nullptr, E);
        node_update<<<nodeGrid, BLK, 0, stream>>>(fagg, fs, b0, nullptr, fh);

        (void)hipMemsetAsync(fagg, 0, (size_t)N_NODES * sizeof(float), stream);
        edge_pass<<<4096, BLK, 0, stream>>>(src, dst, ew, fh, fagg, wn1, E);
        node_update<<<nodeGrid, BLK, 0, stream>>>(fagg, fh, b1, ws1, fh);

        (void)hipMemsetAsync(fagg, 0, (size_t)N_NODES * sizeof(float), stream);
        edge_pass<<<4096, BLK, 0, stream>>>(src, dst, ew, fh, fagg, wn2, E);
        node_update<<<nodeGrid, BLK, 0, stream>>>(fagg, fh, b2, ws2, fh);

        (void)hipMemsetAsync(fhg, 0, NGRAPH * sizeof(float), stream);
        graph_sum<<<512, 256, 0, stream>>>(fh, gid, fhg);
        head_kernel<<<1, 64, 0, stream>>>(fhg, fc1w, fc1b, outw, outb, (float*)d_out);
    }
}

// Round 16
// 407.851 us; speedup vs baseline: 5.8814x; 1.1378x over previous
//
#include <hip/hip_runtime.h>

#define N_NODES 500000
#define NGRAPH  64
#define FDIM    16
#define NB1     62                 // dst bins
#define NPB1    8192               // nodes per bin
#define SH1     13
#define SLC     8                  // slices per bin in bin_pass
#define NBLK    1024               // binning blocks
#define CH      4096               // staged-scatter chunk (edges)
typedef unsigned int u32;
typedef unsigned long long u64;

// ---------- fused: level-1 hist (blocks 0..NBLK-1) + projections (rest) ----------
__global__ __launch_bounds__(1024) void proj_hist(const int* __restrict__ dst, int E, int chunk,
                                                  u32* __restrict__ blockHist,
                                                  const float* __restrict__ x,
                                                  const float* __restrict__ wn,
                                                  const float* __restrict__ wsf,
                                                  float* __restrict__ a,
                                                  float* __restrict__ s) {
    __shared__ u32 cnt[NB1];
    if (blockIdx.x < NBLK) {
        if (threadIdx.x < NB1) cnt[threadIdx.x] = 0;
        __syncthreads();
        int b = blockIdx.x;
        int lo = b * chunk, hi = min(lo + chunk, E);
        int m = (hi - lo) & ~3;
        for (int i = lo + threadIdx.x * 4; i < lo + m; i += 4096) {
            int4 d = *(const int4*)(dst + i);
            atomicAdd(&cnt[((u32)d.x) >> SH1], 1u);
            atomicAdd(&cnt[((u32)d.y) >> SH1], 1u);
            atomicAdd(&cnt[((u32)d.z) >> SH1], 1u);
            atomicAdd(&cnt[((u32)d.w) >> SH1], 1u);
        }
        for (int i = lo + m + threadIdx.x; i < hi; i += 1024)
            atomicAdd(&cnt[((u32)dst[i]) >> SH1], 1u);
        __syncthreads();
        if (threadIdx.x < NB1)
            blockHist[(size_t)b * NB1 + threadIdx.x] = cnt[threadIdx.x];
    } else {
        int i = (blockIdx.x - NBLK) * 1024 + threadIdx.x;
        if (i >= N_NODES) return;
        const float4* xr = (const float4*)(x + (size_t)i * FDIM);
        float4 v0 = xr[0], v1 = xr[1], v2 = xr[2], v3 = xr[3];
        const float4* n4 = (const float4*)wn;
        const float4* s4 = (const float4*)wsf;
        float4 n0 = n4[0], n1 = n4[1], n2 = n4[2], n3 = n4[3];
        float4 w0 = s4[0], w1 = s4[1], w2 = s4[2], w3 = s4[3];
        float an = v0.x*n0.x + v0.y*n0.y + v0.z*n0.z + v0.w*n0.w
                 + v1.x*n1.x + v1.y*n1.y + v1.z*n1.z + v1.w*n1.w
                 + v2.x*n2.x + v2.y*n2.y + v2.z*n2.z + v2.w*n2.w
                 + v3.x*n3.x + v3.y*n3.y + v3.z*n3.z + v3.w*n3.w;
        float as = v0.x*w0.x + v0.y*w0.y + v0.z*w0.z + v0.w*w0.w
                 + v1.x*w1.x + v1.y*w1.y + v1.z*w1.z + v1.w*w1.w
                 + v2.x*w2.x + v2.y*w2.y + v2.z*w2.z + v2.w*w2.w
                 + v3.x*w3.x + v3.y*w3.y + v3.z*w3.z + v3.w*w3.w;
        a[i] = an;
        s[i] = as;
    }
}

// ---------- per-bin exclusive scan over NBLK blocks ----------
__global__ __launch_bounds__(NBLK) void scan1_kernel(u32* __restrict__ blockHist,
                                                     u32* __restrict__ binTotal) {
    int j = blockIdx.x;
    __shared__ u32 lsum[NBLK];
    int t = threadIdx.x;
    u32 v = blockHist[(size_t)t * NB1 + j];
    lsum[t] = v;
    __syncthreads();
    u32 x = v;
    for (int off = 1; off < NBLK; off <<= 1) {
        u32 y = (t >= off) ? lsum[t - off] : 0u;
        __syncthreads();
        x += y; lsum[t] = x;
        __syncthreads();
    }
    if (t == NBLK - 1) binTotal[j] = x;
    blockHist[(size_t)t * NB1 + j] = x - v;
}

// ---------- exclusive scan over bin totals ----------
__global__ void scan2_kernel(const u32* __restrict__ binTotal, u32* __restrict__ binStart) {
    __shared__ u32 sh[64];
    int t = threadIdx.x;
    u32 v = (t < NB1) ? binTotal[t] : 0u;
    sh[t] = v;
    __syncthreads();
    for (int d = 1; d < 64; d <<= 1) {
        u32 y = (t >= d) ? sh[t - d] : 0u;
        __syncthreads();
        sh[t] += y;
        __syncthreads();
    }
    if (t < NB1) binStart[t] = sh[t] - v;
    if (t == 63) binStart[NB1] = sh[63];
}

// ---------- level-1: LDS-staged scatter by dst bin ----------
__global__ __launch_bounds__(512) void scatter1_staged(const int* __restrict__ src,
                                                       const int* __restrict__ dst,
                                                       const float* __restrict__ ew,
                                                       int E, int chunk,
                                                       const u32* __restrict__ blockHist,
                                                       const u32* __restrict__ binStart,
                                                       u64* __restrict__ binned) {
    __shared__ u32 cursor[64];
    __shared__ u32 cnt[64];
    __shared__ u32 off[64];
    __shared__ u64 stage[CH];
    __shared__ unsigned char binOf[CH];
    int b = blockIdx.x, tid = threadIdx.x;
    if (tid < NB1) cursor[tid] = binStart[tid] + blockHist[(size_t)b * NB1 + tid];
    int lo = b * chunk, hiB = min(lo + chunk, E);
    for (int base = lo; base < hiB; base += CH) {
        int n = min(CH, hiB - base);
        if (tid < 64) cnt[tid] = 0;
        __syncthreads();
        u32 rec[8]; float wv[8]; u32 bi[8], rk[8];
#pragma unroll
        for (int k = 0; k < 8; ++k) {
            int idx = base + k * 512 + tid;
            bi[k] = 0xFFFFFFFFu;
            if (idx < base + n) {
                u32 d  = (u32)dst[idx];
                bi[k]  = d >> SH1;
                rec[k] = ((u32)src[idx]) | ((d & (NPB1 - 1)) << 19);
                wv[k]  = ew[idx];
                rk[k]  = atomicAdd(&cnt[bi[k]], 1u);
            }
        }
        __syncthreads();
        if (tid < 64) off[tid] = cnt[tid];
        __syncthreads();
        for (int d2 = 1; d2 < 64; d2 <<= 1) {
            u32 y = 0;
            if (tid < 64 && tid >= d2) y = off[tid - d2];
            __syncthreads();
            if (tid < 64) off[tid] += y;
            __syncthreads();
        }
        if (tid < 64) off[tid] -= cnt[tid];
        __syncthreads();
#pragma unroll
        for (int k = 0; k < 8; ++k) {
            if (bi[k] != 0xFFFFFFFFu) {
                u32 p = off[bi[k]] + rk[k];
                stage[p] = (u64)rec[k] | ((u64)__float_as_uint(wv[k]) << 32);
                binOf[p] = (unsigned char)bi[k];
            }
        }
        __syncthreads();
        for (int p = tid; p < n; p += 512) {
            u32 jj = binOf[p];
            binned[cursor[jj] + ((u32)p - off[jj])] = stage[p];
        }
        __syncthreads();
        if (tid < NB1) cursor[tid] += cnt[tid];
        __syncthreads();
    }
}

// ---------- per-layer: level-1 gather + LDS-atomic accumulate ----------
__global__ __launch_bounds__(512) void bin_pass_g(const u64* __restrict__ binned1,
                                                  const u32* __restrict__ binStart,
                                                  const float* __restrict__ hsrc,
                                                  float* __restrict__ partials) {
    __shared__ float acc[NPB1];
    int j = blockIdx.x / SLC, sl = blockIdx.x % SLC;
    for (int t = threadIdx.x; t < NPB1; t += 512) acc[t] = 0.0f;
    __syncthreads();
    u32 blo = binStart[j], bhi = binStart[j + 1];
    u32 cj = bhi - blo;
    u32 per = (cj + SLC - 1) / SLC;
    u32 lo = blo + sl * per;
    u32 hi = min(lo + per, bhi);
    u32 i = lo + threadIdx.x;
    for (; i + 7u * 512u < hi; i += 8u * 512u) {
        u64 e[8];
#pragma unroll
        for (int k = 0; k < 8; ++k) e[k] = __builtin_nontemporal_load(&binned1[i + (u32)k * 512u]);
        float g[8];
#pragma unroll
        for (int k = 0; k < 8; ++k) g[k] = hsrc[((u32)e[k]) & 0x7FFFFu];
#pragma unroll
        for (int k = 0; k < 8; ++k)
            atomicAdd(&acc[((u32)e[k]) >> 19], g[k] * __uint_as_float((u32)(e[k] >> 32)));
    }
    for (; i < hi; i += 512) {
        u64 e = __builtin_nontemporal_load(&binned1[i]);
        atomicAdd(&acc[((u32)e) >> 19], hsrc[((u32)e) & 0x7FFFFu] * __uint_as_float((u32)(e >> 32)));
    }
    __syncthreads();
    float* p = partials + ((size_t)j * SLC + sl) * NPB1;
    for (int t = threadIdx.x; t < NPB1; t += 512)
        __builtin_nontemporal_store(acc[t], &p[t]);
}

// ---------- merge slices + bias + self-loop + relu ----------
__global__ void merge_update(const float* __restrict__ partials,
                             const float* __restrict__ selfv,
                             const float* __restrict__ wnp,
                             const float* __restrict__ bp,
                             const float* __restrict__ wsp,
                             float* __restrict__ hout) {
    int n = blockIdx.x * blockDim.x + threadIdx.x;
    if (n >= N_NODES) return;
    int j = n >> SH1;
    int l = n & (NPB1 - 1);
    const float* p = partials + (size_t)j * SLC * NPB1 + l;
    float sum = 0.0f;
#pragma unroll
    for (int k = 0; k < SLC; ++k) sum += __builtin_nontemporal_load(&p[k * NPB1]);
    float scale = wnp ? wnp[0] : 1.0f;
    float wself = wsp ? wsp[0] : 1.0f;
    hout[n] = fmaxf(sum * scale + bp[0] + selfv[n] * wself, 0.0f);
}

// ---------- fallback kernels ----------
__global__ void edge_pass(const int* __restrict__ src, const int* __restrict__ dst,
                          const float* __restrict__ ew, const float* __restrict__ h,
                          float* __restrict__ agg, const float* __restrict__ wnp, int E) {
    float scale = wnp ? wnp[0] : 1.0f;
    int stride = gridDim.x * blockDim.x;
    for (int i = blockIdx.x * blockDim.x + threadIdx.x; i < E; i += stride)
        atomicAdd(&agg[dst[i]], h[src[i]] * ew[i] * scale);
}
__global__ void node_update(const float* __restrict__ agg, const float* __restrict__ selfv,
                            const float* __restrict__ bp, const float* __restrict__ wsp,
                            float* __restrict__ hout) {
    int i = blockIdx.x * blockDim.x + threadIdx.x;
    if (i >= N_NODES) return;
    float wsc = wsp ? wsp[0] : 1.0f;
    hout[i] = fmaxf(agg[i] + bp[0] + selfv[i] * wsc, 0.0f);
}
__global__ void proj_kernel(const float* __restrict__ x, const float* __restrict__ wn,
                            const float* __restrict__ wsf, float* __restrict__ a,
                            float* __restrict__ s) {
    int i = blockIdx.x * blockDim.x + threadIdx.x;
    if (i >= N_NODES) return;
    float an = 0.f, as = 0.f;
    for (int k = 0; k < FDIM; ++k) {
        float v = x[(size_t)i * FDIM + k];
        an += v * wn[k]; as += v * wsf[k];
    }
    a[i] = an; s[i] = as;
}

// ---------- per-graph sum (gid sorted; wave-uniform fast path) ----------
__global__ __launch_bounds__(256) void graph_sum(const float* __restrict__ h,
                                                 const int* __restrict__ gid,
                                                 float* __restrict__ hg) {
    __shared__ float loc[NGRAPH];
    int t = threadIdx.x;
    if (t < NGRAPH) loc[t] = 0.0f;
    __syncthreads();
    int nq = N_NODES / 4;
    int stride = gridDim.x * blockDim.x;
    for (int q = blockIdx.x * blockDim.x + t; q < nq; q += stride) {
        int4   g4 = *(const int4*)(gid + 4 * q);
        float4 h4 = *(const float4*)(h + 4 * q);
        int g0 = __shfl(g4.x, 0);
        bool uni = (g4.x == g0) & (g4.w == g0);
        if (__all(uni)) {
            float v = h4.x + h4.y + h4.z + h4.w;
#pragma unroll
            for (int o = 32; o > 0; o >>= 1) v += __shfl_down(v, o);
            if ((t & 63) == 0) atomicAdd(&loc[g0], v);
        } else {
            atomicAdd(&loc[g4.x], h4.x);
            atomicAdd(&loc[g4.y], h4.y);
            atomicAdd(&loc[g4.z], h4.z);
            atomicAdd(&loc[g4.w], h4.w);
        }
    }
    __syncthreads();
    if (t < NGRAPH) atomicAdd(&hg[t], loc[t]);
}

// ---------- head MLP + log_softmax ----------
__global__ void head_kernel(const float* __restrict__ hg,
                            const float* __restrict__ fc1w, const float* __restrict__ fc1b,
                            const float* __restrict__ outw, const float* __restrict__ outb,
                            float* __restrict__ out) {
    int g = threadIdx.x;
    if (g >= NGRAPH) return;
    float v = hg[g];
    float t[8];
#pragma unroll
    for (int j = 0; j < 8; ++j) {
        float z = (v * fc1w[j] + fc1b[j]) * 1000.0f;
        t[j] = 1.0f / (1.0f + expf(-z));
    }
    float o[4];
#pragma unroll
    for (int k = 0; k < 4; ++k) {
        float acc2 = outb[k];
#pragma unroll
        for (int j = 0; j < 8; ++j) acc2 += t[j] * outw[k * 8 + j];
        o[k] = fmaxf(acc2, 0.0f);
    }
    float m = fmaxf(fmaxf(o[0], o[1]), fmaxf(o[2], o[3]));
    float se = 0.0f;
#pragma unroll
    for (int k = 0; k < 4; ++k) se += expf(o[k] - m);
    float lse = m + logf(se);
#pragma unroll
    for (int k = 0; k < 4; ++k) out[g * 4 + k] = o[k] - lse;
}

extern "C" void kernel_launch(void* const* d_in, const int* in_sizes, int n_in,
                              void* d_out, int out_size, void* d_ws, size_t ws_size,
                              hipStream_t stream) {
    const float* x    = (const float*)d_in[0];
    const int*   src  = (const int*)  d_in[1];
    const int*   dst  = (const int*)  d_in[2];
    const int*   gid  = (const int*)  d_in[3];
    const float* ew   = (const float*)d_in[4];
    const float* wn0  = (const float*)d_in[6];
    const float* b0   = (const float*)d_in[7];
    const float* ws0  = (const float*)d_in[8];
    const float* wn1  = (const float*)d_in[9];
    const float* b1   = (const float*)d_in[10];
    const float* ws1  = (const float*)d_in[11];
    const float* wn2  = (const float*)d_in[12];
    const float* b2   = (const float*)d_in[13];
    const float* ws2  = (const float*)d_in[14];
    const float* fc1w = (const float*)d_in[15];
    const float* fc1b = (const float*)d_in[16];
    const float* outw = (const float*)d_in[17];
    const float* outb = (const float*)d_in[18];
    int E = in_sizes[1];

    const int BLK = 256;
    int nodeGrid = (N_NODES + BLK - 1) / BLK;
    char* ws = (char*)d_ws;

    size_t off = 0;
    u64* binned1    = (u64*)(ws + off); off += (size_t)E * 8;
    u32* blockHist  = (u32*)(ws + off); off += (size_t)NBLK * NB1 * 4;
    u32* binStart   = (u32*)(ws + off); off += (NB1 + 2) * 4;
    off = (off + 63) & ~(size_t)63;
    u32* binTotal   = (u32*)(ws + off); off += (NB1 + 2) * 4;
    off = (off + 63) & ~(size_t)63;
    float* partials = (float*)(ws + off); off += (size_t)NB1 * SLC * NPB1 * 4;
    float* a  = (float*)(ws + off); off += (size_t)N_NODES * 4;
    float* s  = (float*)(ws + off); off += (size_t)N_NODES * 4;
    float* h0 = (float*)(ws + off); off += (size_t)N_NODES * 4;
    float* h1 = (float*)(ws + off); off += (size_t)N_NODES * 4;
    float* hg = (float*)(ws + off); off += 256;
    size_t need = off;

    if (ws_size >= need) {
        int chunk = (((E + NBLK - 1) / NBLK) + 3) & ~3;
        int projBlocks = (N_NODES + 1023) / 1024;

        proj_hist<<<NBLK + projBlocks, 1024, 0, stream>>>(dst, E, chunk, blockHist,
                                                          x, wn0, ws0, a, s);
        scan1_kernel<<<NB1, NBLK, 0, stream>>>(blockHist, binTotal);
        scan2_kernel<<<1, 64, 0, stream>>>(binTotal, binStart);
        scatter1_staged<<<NBLK, 512, 0, stream>>>(src, dst, ew, E, chunk, blockHist,
                                                  binStart, binned1);

        bin_pass_g<<<NB1 * SLC, 512, 0, stream>>>(binned1, binStart, a, partials);
        merge_update<<<nodeGrid, BLK, 0, stream>>>(partials, s, nullptr, b0, nullptr, h0);
        bin_pass_g<<<NB1 * SLC, 512, 0, stream>>>(binned1, binStart, h0, partials);
        merge_update<<<nodeGrid, BLK, 0, stream>>>(partials, h0, wn1, b1, ws1, h1);
        bin_pass_g<<<NB1 * SLC, 512, 0, stream>>>(binned1, binStart, h1, partials);
        merge_update<<<nodeGrid, BLK, 0, stream>>>(partials, h1, wn2, b2, ws2, h0);

        (void)hipMemsetAsync(hg, 0, NGRAPH * sizeof(float), stream);
        graph_sum<<<512, 256, 0, stream>>>(h0, gid, hg);
        head_kernel<<<1, 64, 0, stream>>>(hg, fc1w, fc1b, outw, outb, (float*)d_out);
    } else {
        float* wsb  = (float*)d_ws;
        float* fa   = wsb;
        float* fs   = wsb + 1 * (size_t)N_NODES;
        float* fagg = wsb + 2 * (size_t)N_NODES;
        float* fh   = wsb + 3 * (size_t)N_NODES;
        float* fhg  = wsb + 4 * (size_t)N_NODES;

        proj_kernel<<<nodeGrid, BLK, 0, stream>>>(x, wn0, ws0, fa, fs);

        (void)hipMemsetAsync(fagg, 0, (size_t)N_NODES * sizeof(float), stream);
        edge_pass<<<4096, BLK, 0, stream>>>(src, dst, ew, fa, fagg, nullptr, E);
        node_update<<<nodeGrid, BLK, 0, stream>>>(fagg, fs, b0, nullptr, fh);

        (void)hipMemsetAsync(fagg, 0, (size_t)N_NODES * sizeof(float), stream);
        edge_pass<<<4096, BLK, 0, stream>>>(src, dst, ew, fh, fagg, wn1, E);
        node_update<<<nodeGrid, BLK, 0, stream>>>(fagg, fh, b1, ws1, fh);

        (void)hipMemsetAsync(fagg, 0, (size_t)N_NODES * sizeof(float), stream);
        edge_pass<<<4096, BLK, 0, stream>>>(src, dst, ew, fh, fagg, wn2, E);
        node_update<<<nodeGrid, BLK, 0, stream>>>(fagg, fh, b2, ws2, fh);

        (void)hipMemsetAsync(fhg, 0, NGRAPH * sizeof(float), stream);
        graph_sum<<<512, 256, 0, stream>>>(fh, gid, fhg);
        head_kernel<<<1, 64, 0, stream>>>(fhg, fc1w, fc1b, outw, outb, (float*)d_out);
    }
}